// Round 6
// baseline (4077.199 us; speedup 1.0000x reference)
//
#include <hip/hip_runtime.h>
#include <hip/hip_bf16.h>
#include <math.h>

#define BATCH   512
#define IN_DIM  4096
#define HID_DIM 8192
#define OUT_DIM 1024
#define T_STEPS 10
#define LEAK    0.95f

typedef __attribute__((ext_vector_type(8))) short bf16x8;
typedef __attribute__((ext_vector_type(8))) unsigned short ushort8;
typedef __attribute__((ext_vector_type(4))) float floatx4;

#define GLB_AS __attribute__((address_space(1)))
#define LDS_AS __attribute__((address_space(3)))

// async 16B/lane global->LDS: lds dest = wave-uniform base + lane*16
#define ASYNC_COPY16(gp, lp)                                                  \
    __builtin_amdgcn_global_load_lds((const GLB_AS unsigned int*)(gp),        \
                                     (LDS_AS unsigned int*)(lp), 16, 0, 0)

__device__ __forceinline__ unsigned short f2bf(float f) {
    unsigned int u = __float_as_uint(f);
    u += 0x7fffu + ((u >> 16) & 1u);   // RNE
    return (unsigned short)(u >> 16);
}

// ---------------------------------------------------------------------------
// r = bf16(sigmoid(x)), 4 elems/thread
// ---------------------------------------------------------------------------
__global__ __launch_bounds__(256) void rates_bf16(const float* __restrict__ x,
                                                  unsigned short* __restrict__ r, int n4) {
    int i = blockIdx.x * blockDim.x + threadIdx.x;
    if (i >= n4) return;
    float4 v = ((const float4*)x)[i];
    ushort4 o;
    o.x = f2bf(1.f / (1.f + __expf(-v.x)));
    o.y = f2bf(1.f / (1.f + __expf(-v.y)));
    o.z = f2bf(1.f / (1.f + __expf(-v.z)));
    o.w = f2bf(1.f / (1.f + __expf(-v.w)));
    ((ushort4*)r)[i] = o;
}

// ---------------------------------------------------------------------------
// transpose + convert: in fp32 [K][N] -> out bf16 [N][K]; 64x64 tiles.
// ---------------------------------------------------------------------------
__global__ __launch_bounds__(256) void transpose_cvt(const float* __restrict__ in,
                                                     unsigned short* __restrict__ out,
                                                     int K, int N) {
    __shared__ float tile[64][65];
    const int nb = blockIdx.x * 64;
    const int kb = blockIdx.y * 64;
    const int t = threadIdx.x;
    const int tr = t >> 4;
    const int tc4 = (t & 15) * 4;
#pragma unroll
    for (int it = 0; it < 4; ++it) {
        int k = tr + 16 * it;
        float4 v = *(const float4*)&in[(size_t)(kb + k) * N + nb + tc4];
        tile[k][tc4 + 0] = v.x;
        tile[k][tc4 + 1] = v.y;
        tile[k][tc4 + 2] = v.z;
        tile[k][tc4 + 3] = v.w;
    }
    __syncthreads();
    const int k8 = (t & 7) * 8;
    const int nr = t >> 3;          // 0..31
#pragma unroll
    for (int it = 0; it < 2; ++it) {
        int n = nr + 32 * it;
        ushort8 o;
#pragma unroll
        for (int j = 0; j < 8; ++j) o[j] = f2bf(tile[k8 + j][n]);
        *(ushort8*)&out[(size_t)(nb + n) * K + kb + k8] = o;
    }
}

// ---------------------------------------------------------------------------
// bf16 MFMA GEMM: C[M,N] = A[M,K] @ Bt[N,K]^T
// 64M x 64N tile, BK=64, 256 threads = 4 waves in 2x2 quadrants (32M x 32N).
// 16 KB single-buffered LDS -> 1024 blocks, 4 blocks/CU, 16 waves/CU: enough
// independent barrier-phases to overlap each other's vmcnt(0) drains.
// LDS in fragment-order chunks (conflict-free): chunk (rc,kc) holds rows
// rc*16..+15 x k kc*32..+31, lane l owns (row=l&15, kgroup=l>>4) -> fragment
// reads are chunkbase + lane*16B (2-way, free).
// ---------------------------------------------------------------------------
__global__ __launch_bounds__(256) void gemm_bf16(const unsigned short* __restrict__ A,
                                                 const unsigned short* __restrict__ Bt,
                                                 float* __restrict__ C,
                                                 int M, int N, int K) {
    __shared__ unsigned short As[8 * 512];   // 4 rowchunks x 2 kchunks
    __shared__ unsigned short Bs[8 * 512];

    const int tid = threadIdx.x;
    const int wave = tid >> 6;
    const int lane = tid & 63;
    const int wr = wave >> 1;      // M half (32 rows)
    const int wc = wave & 1;       // N half (32 cols)

    const int m0 = blockIdx.y * 64;
    const int n0 = blockIdx.x * 64;

    // staging: wave w stages A rowchunk rc=w (kc=0,1) and B rowchunk rc=w
    const int ar = lane & 15;
    const int ac = (lane >> 4) * 8;
    const unsigned short* agp = A + (size_t)(m0 + wave * 16 + ar) * K + ac;
    const unsigned short* bgp = Bt + (size_t)(n0 + wave * 16 + ar) * K + ac;
    unsigned short* asl = &As[wave * 1024];
    unsigned short* bsl = &Bs[wave * 1024];

    const int fr = lane & 15;
    const int fq = lane >> 4;
    floatx4 acc[2][2] = {};

    for (int k0 = 0; k0 < K; k0 += 64) {
        __syncthreads();
        ASYNC_COPY16(agp + k0, asl);            // A rc=w, kc=0
        ASYNC_COPY16(agp + k0 + 32, asl + 512); // A rc=w, kc=1
        ASYNC_COPY16(bgp + k0, bsl);            // B rc=w, kc=0
        ASYNC_COPY16(bgp + k0 + 32, bsl + 512); // B rc=w, kc=1
        __syncthreads();
#pragma unroll
        for (int kc = 0; kc < 2; ++kc) {
            bf16x8 af[2], bfr[2];
#pragma unroll
            for (int i = 0; i < 2; ++i)
                af[i] = *(const bf16x8*)&As[((wr * 2 + i) * 2 + kc) * 512 + lane * 8];
#pragma unroll
            for (int j = 0; j < 2; ++j)
                bfr[j] = *(const bf16x8*)&Bs[((wc * 2 + j) * 2 + kc) * 512 + lane * 8];
#pragma unroll
            for (int i = 0; i < 2; ++i)
#pragma unroll
                for (int j = 0; j < 2; ++j)
                    acc[i][j] = __builtin_amdgcn_mfma_f32_16x16x32_bf16(af[i], bfr[j], acc[i][j], 0, 0, 0);
        }
    }

#pragma unroll
    for (int i = 0; i < 2; ++i) {
#pragma unroll
        for (int j = 0; j < 2; ++j) {
            int row = m0 + wr * 32 + i * 16 + fq * 4;
            int col = n0 + wc * 32 + j * 16 + fr;
#pragma unroll
            for (int r = 0; r < 4; ++r)
                C[(size_t)(row + r) * N + col] = acc[i][j][r];
        }
    }
}

// ---------------------------------------------------------------------------
// First-spike scan (exact structural reduction: REFRACT=1 & t=spike_count =>
// each neuron spikes at most once ever; adaptation unreachable). Finds the
// batch index of the single spike (or -1). Wave-level early exit.
// ---------------------------------------------------------------------------
__global__ __launch_bounds__(256) void first_spike(const float* __restrict__ cur,
                                                   int* __restrict__ b_fire, int n) {
    int j = blockIdx.x * blockDim.x + threadIdx.x;
    float v = 0.f;
    bool fired = false;
    int bf = -1;
    for (int b = 0; b < BATCH; ++b) {
        float c = cur[(size_t)b * n + j];
#pragma unroll
        for (int t = 0; t < T_STEPS; ++t) {
            v = v * LEAK + c;
            if (!fired && v >= 1.0f) { fired = true; bf = b; }
        }
        if (__all((int)fired)) break;
    }
    b_fire[j] = bf;
}

// ---------------------------------------------------------------------------
// Sparse layer-2 "GEMM": cur_o[b][k] = 0.1 * sum_{j: bfire[j]==b} W_ho[j][k].
// Exact (fp32 W_ho, untransposed, each row read at most once device-wide).
// Block b accumulates its 1024 k's in registers; bfire reads broadcast.
// ---------------------------------------------------------------------------
__global__ __launch_bounds__(256) void scatter_gemm(const int* __restrict__ bfire,
                                                    const float* __restrict__ W_ho,
                                                    float* __restrict__ cur_o) {
    const int b = blockIdx.x;
    const int k4 = threadIdx.x * 4;
    float4 acc = make_float4(0.f, 0.f, 0.f, 0.f);
    for (int j0 = 0; j0 < HID_DIM; j0 += 4) {
        int4 f = *(const int4*)&bfire[j0];   // same addr across block: broadcast
#pragma unroll
        for (int u = 0; u < 4; ++u) {
            int fj = (u == 0) ? f.x : (u == 1) ? f.y : (u == 2) ? f.z : f.w;
            if (fj == b) {                    // block-uniform branch
                float4 w = *(const float4*)&W_ho[(size_t)(j0 + u) * OUT_DIM + k4];
                acc.x += w.x; acc.y += w.y; acc.z += w.z; acc.w += w.w;
            }
        }
    }
    acc.x *= 0.1f; acc.y *= 0.1f; acc.z *= 0.1f; acc.w *= 0.1f;
    *(float4*)&cur_o[(size_t)b * OUT_DIM + k4] = acc;
}

// out[b][k] = (b_fire[k]==b) ? 0.1f : 0, fp32, 4 elems/thread
__global__ __launch_bounds__(256) void write_out_f32(const int* __restrict__ b_fire,
                                                     float* __restrict__ out) {
    int gid = blockIdx.x * blockDim.x + threadIdx.x;       // over B*OUT/4
    int b = gid >> 8;                                      // OUT/4 = 256
    int k = (gid & 255) << 2;
    int4 bf = *(const int4*)&b_fire[k];
    float4 o;
    o.x = (bf.x == b) ? 0.1f : 0.f;
    o.y = (bf.y == b) ? 0.1f : 0.f;
    o.z = (bf.z == b) ? 0.1f : 0.f;
    o.w = (bf.w == b) ? 0.1f : 0.f;
    *(float4*)&out[(size_t)b * OUT_DIM + k] = o;
}

// ---------------------------------------------------------------------------
extern "C" void kernel_launch(void* const* d_in, const int* in_sizes, int n_in,
                              void* d_out, int out_size, void* d_ws, size_t ws_size,
                              hipStream_t stream) {
    const float* x    = (const float*)d_in[0];  // [512, 4096]
    const float* W_ih = (const float*)d_in[1];  // [4096, 8192]
    const float* W_ho = (const float*)d_in[2];  // [8192, 1024]
    float* out = (float*)d_out;                 // [512, 1024] fp32

    char* base = (char*)d_ws;
    float*          cur_h   = (float*)(base + 0);                  // 16.8 MB
    unsigned short* r_bf    = (unsigned short*)(base + 16777216);  //  4.2 MB
    int*            bfire_h = (int*)(base + 20971520);             //  32 KB
    int*            bfire_o = (int*)(base + 21004288);             //   4 KB
    float*          cur_o   = (float*)(base + 21008384);           //   2 MB
    unsigned short* Wt      = (unsigned short*)(base + 31457280);  // 67.1 MB (proven bound)

    // 1) input rates -> bf16 [512][4096]
    int n4 = BATCH * IN_DIM / 4;
    rates_bf16<<<n4 / 256, 256, 0, stream>>>(x, r_bf, n4);

    // 2) Wt = bf16(W_ih^T)  [8192][4096]
    transpose_cvt<<<dim3(HID_DIM / 64, IN_DIM / 64), 256, 0, stream>>>(W_ih, Wt, IN_DIM, HID_DIM);

    // 3) cur_h = r_bf @ Wt^T  [512][8192]; 64x64 tiles -> 1024 blocks, 4/CU
    gemm_bf16<<<dim3(HID_DIM / 64, BATCH / 64), 256, 0, stream>>>(
        r_bf, Wt, cur_h, BATCH, HID_DIM, IN_DIM);

    // 4) hidden first-spike scan -> bfire_h [8192]
    first_spike<<<HID_DIM / 256, 256, 0, stream>>>(cur_h, bfire_h, HID_DIM);

    // 5) sparse layer 2: cur_o[b][k] = 0.1 * sum_{bfire_h[j]==b} W_ho[j][k]
    scatter_gemm<<<BATCH, 256, 0, stream>>>(bfire_h, W_ho, cur_o);

    // 6) output first-spike scan -> bfire_o [1024]
    first_spike<<<OUT_DIM / 256, 256, 0, stream>>>(cur_o, bfire_o, OUT_DIM);

    // 7) d_out [512][1024] fp32 (wide, coalesced)
    write_out_f32<<<(BATCH * OUT_DIM / 4) / 256, 256, 0, stream>>>(bfire_o, out);
}